// Round 3
// baseline (233.832 us; speedup 1.0000x reference)
//
#include <hip/hip_runtime.h>
#include <hip/hip_bf16.h>

typedef __attribute__((ext_vector_type(8))) __bf16 bf16x8;
typedef __attribute__((ext_vector_type(4))) __bf16 bf16x4;
typedef __attribute__((ext_vector_type(4))) float f32x4;

#define MFMA16(a, b, c) __builtin_amdgcn_mfma_f32_16x16x32_bf16((a), (b), (c), 0, 0, 0)

static constexpr int DM = 1024;
static constexpr int SEQ = 2048;
static constexpr int NB = 2;
static constexpr int NH = 16;
static constexpr int DKK = 64;
static constexpr int MROWS = NB * SEQ;  // 4096

// ---------------- Fused Q/K/V projection GEMM (z selects which) ----------------
// Q/K: Y[b,h,s,dk] (bf16).  V: transposed tiles Yt[bh][s>>6][dk][s&63] (bf16).
__global__ __launch_bounds__(256) void proj3_kernel(
    const float* __restrict__ Xq, const float* __restrict__ Xk,
    const float* __restrict__ Xv, const float* __restrict__ Wq,
    const float* __restrict__ Wk, const float* __restrict__ Wv,
    __bf16* __restrict__ Yq, __bf16* __restrict__ Yk, __bf16* __restrict__ Yv) {
  __shared__ __bf16 As[128][40];
  __shared__ __bf16 Bs[128][40];
  const int z = blockIdx.z;
  const float* X = (z == 0) ? Xq : (z == 1) ? Xk : Xv;
  const float* W = (z == 0) ? Wq : (z == 1) ? Wk : Wv;
  __bf16* Y = (z == 0) ? Yq : (z == 1) ? Yk : Yv;
  const int tid = threadIdx.x;
  const int lane = tid & 63;
  const int wv = tid >> 6;
  const int wm = (wv >> 1) * 64;
  const int wn = (wv & 1) * 64;
  const int bm = blockIdx.y * 128;
  const int bn = blockIdx.x * 128;
  const int g = lane >> 4, c = lane & 15;
  const int srow = tid >> 1;          // 0..127
  const int shalf = (tid & 1) * 16;   // 0 or 16
  f32x4 acc[4][4] = {};
  const float* ap0 = X + (size_t)(bm + srow) * DM + shalf;
  const float* bp0 = W + (size_t)(bn + srow) * DM + shalf;
  for (int k0 = 0; k0 < DM; k0 += 32) {
    f32x4 xa[4], xb[4];
#pragma unroll
    for (int i = 0; i < 4; ++i) {
      xa[i] = *(const f32x4*)(ap0 + k0 + i * 4);
      xb[i] = *(const f32x4*)(bp0 + k0 + i * 4);
    }
    bf16x8 ha[2], hb[2];
#pragma unroll
    for (int i = 0; i < 2; ++i)
#pragma unroll
      for (int j = 0; j < 8; ++j) {
        ha[i][j] = (__bf16)xa[i * 2 + (j >> 2)][j & 3];
        hb[i][j] = (__bf16)xb[i * 2 + (j >> 2)][j & 3];
      }
    *(bf16x8*)&As[srow][shalf] = ha[0];
    *(bf16x8*)&As[srow][shalf + 8] = ha[1];
    *(bf16x8*)&Bs[srow][shalf] = hb[0];
    *(bf16x8*)&Bs[srow][shalf + 8] = hb[1];
    __syncthreads();
    bf16x8 af[4], bfr[4];
#pragma unroll
    for (int i = 0; i < 4; ++i) {
      af[i] = *(const bf16x8*)&As[wm + i * 16 + c][g * 8];
      bfr[i] = *(const bf16x8*)&Bs[wn + i * 16 + c][g * 8];
    }
#pragma unroll
    for (int mi = 0; mi < 4; ++mi)
#pragma unroll
      for (int ni = 0; ni < 4; ++ni)
        acc[mi][ni] = MFMA16(af[mi], bfr[ni], acc[mi][ni]);
    __syncthreads();
  }
  if (z == 2) {
    // V: transposed-tile layout [bh][s>>6][dk][s&63]; r-contiguous b64 stores
#pragma unroll
    for (int mi = 0; mi < 4; ++mi)
#pragma unroll
      for (int ni = 0; ni < 4; ++ni) {
        const int row = bm + wm + mi * 16 + g * 4;  // +r
        const int col = bn + wn + ni * 16 + c;
        const int b = row >> 11;
        const int s = row & (SEQ - 1);
        const int h = col >> 6;
        const int dk = col & 63;
        bf16x4 st;
#pragma unroll
        for (int r = 0; r < 4; ++r) st[r] = (__bf16)acc[mi][ni][r];
        *(bf16x4*)&Yv[((size_t)((b * NH + h) * 32 + (s >> 6)) << 12) +
                      dk * 64 + (s & 63)] = st;
      }
  } else {
#pragma unroll
    for (int mi = 0; mi < 4; ++mi)
#pragma unroll
      for (int ni = 0; ni < 4; ++ni)
#pragma unroll
        for (int r = 0; r < 4; ++r) {
          const int row = bm + wm + mi * 16 + g * 4 + r;
          const int col = bn + wn + ni * 16 + c;
          const int b = row >> 11;
          const int s = row & (SEQ - 1);
          const int h = col >> 6;
          const int dk = col & 63;
          Y[((size_t)((b * NH + h) * SEQ + s) << 6) + dk] = (__bf16)acc[mi][ni][r];
        }
  }
}

// ---------------- Output GEMM ----------------
__global__ __launch_bounds__(256) void out_gemm_kernel(
    const __bf16* __restrict__ X, const float* __restrict__ W,
    float* __restrict__ Y) {
  __shared__ __bf16 As[128][40];
  __shared__ __bf16 Bs[128][40];
  const int tid = threadIdx.x;
  const int lane = tid & 63;
  const int wv = tid >> 6;
  const int wm = (wv >> 1) * 64;
  const int wn = (wv & 1) * 64;
  const int bm = blockIdx.y * 128;
  const int bn = blockIdx.x * 128;
  const int g = lane >> 4, c = lane & 15;
  const int srow = tid >> 1;
  const int shalf = (tid & 1) * 16;
  f32x4 acc[4][4] = {};
  const __bf16* xp0 = X + (size_t)(bm + srow) * DM + shalf;
  const float* bp0 = W + (size_t)(bn + srow) * DM + shalf;
  for (int k0 = 0; k0 < DM; k0 += 32) {
    bf16x8 ha0 = *(const bf16x8*)(xp0 + k0);
    bf16x8 ha1 = *(const bf16x8*)(xp0 + k0 + 8);
    f32x4 xb[4];
#pragma unroll
    for (int i = 0; i < 4; ++i) xb[i] = *(const f32x4*)(bp0 + k0 + i * 4);
    bf16x8 hb[2];
#pragma unroll
    for (int i = 0; i < 2; ++i)
#pragma unroll
      for (int j = 0; j < 8; ++j) hb[i][j] = (__bf16)xb[i * 2 + (j >> 2)][j & 3];
    *(bf16x8*)&As[srow][shalf] = ha0;
    *(bf16x8*)&As[srow][shalf + 8] = ha1;
    *(bf16x8*)&Bs[srow][shalf] = hb[0];
    *(bf16x8*)&Bs[srow][shalf + 8] = hb[1];
    __syncthreads();
    bf16x8 af[4], bfr[4];
#pragma unroll
    for (int i = 0; i < 4; ++i) {
      af[i] = *(const bf16x8*)&As[wm + i * 16 + c][g * 8];
      bfr[i] = *(const bf16x8*)&Bs[wn + i * 16 + c][g * 8];
    }
#pragma unroll
    for (int mi = 0; mi < 4; ++mi)
#pragma unroll
      for (int ni = 0; ni < 4; ++ni)
        acc[mi][ni] = MFMA16(af[mi], bfr[ni], acc[mi][ni]);
    __syncthreads();
  }
#pragma unroll
  for (int mi = 0; mi < 4; ++mi)
#pragma unroll
    for (int ni = 0; ni < 4; ++ni)
#pragma unroll
      for (int r = 0; r < 4; ++r) {
        const int row = bm + wm + mi * 16 + g * 4 + r;
        const int col = bn + wn + ni * 16 + c;
        Y[(size_t)row * DM + col] = acc[mi][ni][r];
      }
}

// ---------------- Causal flash attention (barrier-free) ----------------
// Q,K: (B,H,S,64) bf16.  V: transposed tiles [bh][32][64][64].  O: (B,S,1024).
// 4 waves/block, each wave independent: 32 q-rows (2 fragments of 16).
// All MFMA operands read coalesced directly from global; only LDS use is the
// wave-private P round-trip (no __syncthreads anywhere).
__global__ __launch_bounds__(256) void attn_kernel(
    const __bf16* __restrict__ Qw, const __bf16* __restrict__ Kw,
    const __bf16* __restrict__ Vtw, __bf16* __restrict__ Ow) {
  __shared__ __bf16 Pl[128][72];
  const int tid = threadIdx.x;
  const int lane = tid & 63;
  const int wv = tid >> 6;
  const int g = lane >> 4, c = lane & 15;
  // chunked XCD swizzle (512 % 8 == 0 -> bijective): each XCD gets 4 heads.
  const int bid = blockIdx.x;
  const int swz = (bid & 7) * 64 + (bid >> 3);
  const int bh = swz >> 4;             // 0..31
  const int qt = 15 - (swz & 15);      // heavy-first within chunk
  const size_t base = (size_t)bh * SEQ * DKK;
  const int qbase = qt * 128 + wv * 32;
  bf16x8 qf[2][2];
#pragma unroll
  for (int f = 0; f < 2; ++f) {
    const __bf16* qp = Qw + base + (size_t)(qbase + f * 16 + c) * DKK + g * 8;
    qf[f][0] = *(const bf16x8*)qp;
    qf[f][1] = *(const bf16x8*)(qp + 32);
  }
  f32x4 oacc[4][2] = {};
  float m_r[2] = {-3e38f, -3e38f};
  float l_r[2] = {0.f, 0.f};
  const int NT = 2 * qt + (wv >> 1) + 1;  // causal tile count for this wave
  const __bf16* Kb = Kw + base;
  const __bf16* Vb = Vtw + base;
  __bf16* PlW = &Pl[wv * 32][0];
  const float scl = 0.125f * 1.44269504f;  // 1/sqrt(64) * log2(e)
  for (int t = 0; t < NT; ++t) {
    const __bf16* Kt = Kb + (size_t)t * (64 * DKK);
    f32x4 s0[4], s1[4];
#pragma unroll
    for (int m = 0; m < 4; ++m) {
      const __bf16* kp = Kt + (m * 16 + c) * DKK + g * 8;
      bf16x8 kb0 = *(const bf16x8*)kp;
      bf16x8 kb1 = *(const bf16x8*)(kp + 32);
      f32x4 z0 = {}, z1 = {};
      z0 = MFMA16(kb0, qf[0][0], z0);
      s0[m] = MFMA16(kb1, qf[0][1], z0);
      z1 = MFMA16(kb0, qf[1][0], z1);
      s1[m] = MFMA16(kb1, qf[1][1], z1);
    }
    const bool masked = (t == NT - 1);
    const int kvb = t * 64;
#pragma unroll
    for (int f = 0; f < 2; ++f) {
      f32x4* sac = (f == 0) ? s0 : s1;  // f is compile-time (unrolled)
      const int q = qbase + f * 16 + c;
      float mx = -3e38f;
#pragma unroll
      for (int m = 0; m < 4; ++m)
#pragma unroll
        for (int r = 0; r < 4; ++r) {
          float x = sac[m][r] * scl;
          if (masked && (kvb + m * 16 + g * 4 + r > q)) x = -3e38f;
          sac[m][r] = x;
          mx = fmaxf(mx, x);
        }
      mx = fmaxf(mx, __shfl_xor(mx, 16, 64));
      mx = fmaxf(mx, __shfl_xor(mx, 32, 64));
      const float mn = fmaxf(m_r[f], mx);
      const float al = exp2f(m_r[f] - mn);
      m_r[f] = mn;
      float rs = 0.f;
#pragma unroll
      for (int m = 0; m < 4; ++m) {
        bf16x4 pq;
#pragma unroll
        for (int r = 0; r < 4; ++r) {
          const float p = exp2f(sac[m][r] - mn);
          rs += p;
          pq[r] = (__bf16)p;
        }
        *(bf16x4*)(PlW + (f * 16 + c) * 72 + m * 16 + g * 4) = pq;
      }
      rs += __shfl_xor(rs, 16, 64);
      rs += __shfl_xor(rs, 32, 64);
      l_r[f] = l_r[f] * al + rs;
#pragma unroll
      for (int ob = 0; ob < 4; ++ob)
#pragma unroll
        for (int r = 0; r < 4; ++r) oacc[ob][f][r] *= al;
    }
    // O^T += V^T P^T  (V^T tiles direct from global, coalesced)
    const __bf16* Vt = Vb + (size_t)t * (64 * 64);
    bf16x8 pf[2][2];
#pragma unroll
    for (int f = 0; f < 2; ++f)
#pragma unroll
      for (int h = 0; h < 2; ++h)
        pf[f][h] = *(const bf16x8*)(PlW + (f * 16 + c) * 72 + h * 32 + g * 8);
#pragma unroll
    for (int ob = 0; ob < 4; ++ob) {
      const __bf16* vp = Vt + (ob * 16 + c) * 64;
#pragma unroll
      for (int h = 0; h < 2; ++h) {
        bf16x8 va = *(const bf16x8*)(vp + h * 32 + g * 8);
        oacc[ob][0] = MFMA16(va, pf[0][h], oacc[ob][0]);
        oacc[ob][1] = MFMA16(va, pf[1][h], oacc[ob][1]);
      }
    }
  }
  const int b = bh >> 4, h = bh & 15;
#pragma unroll
  for (int f = 0; f < 2; ++f) {
    const int q = qbase + f * 16 + c;
    const float inv = 1.0f / l_r[f];
#pragma unroll
    for (int ob = 0; ob < 4; ++ob) {
      bf16x4 st;
#pragma unroll
      for (int r = 0; r < 4; ++r) st[r] = (__bf16)(oacc[ob][f][r] * inv);
      *(bf16x4*)&Ow[(size_t)(b * SEQ + q) * DM + h * 64 + ob * 16 + g * 4] = st;
    }
  }
}

extern "C" void kernel_launch(void* const* d_in, const int* in_sizes, int n_in,
                              void* d_out, int out_size, void* d_ws,
                              size_t ws_size, hipStream_t stream) {
  const float* q = (const float*)d_in[0];
  const float* k = (const float*)d_in[1];
  const float* v = (const float*)d_in[2];
  // d_in[3] = mask (tril) — causality is hard-coded in attn_kernel
  const float* Wq = (const float*)d_in[4];
  const float* Wk = (const float*)d_in[5];
  const float* Wv = (const float*)d_in[6];
  const float* Wo = (const float*)d_in[7];
  __bf16* ws = (__bf16*)d_ws;
  const size_t SZ = (size_t)NB * NH * SEQ * DKK;  // 4,194,304 elems
  __bf16* qws = ws;
  __bf16* kws = ws + SZ;
  __bf16* vws = ws + 2 * SZ;   // transposed-tile layout
  __bf16* ows = ws + 3 * SZ;
  proj3_kernel<<<dim3(DM / 128, MROWS / 128, 3), 256, 0, stream>>>(
      q, k, v, Wq, Wk, Wv, qws, kws, vws);
  attn_kernel<<<dim3(512), 256, 0, stream>>>(qws, kws, vws, ows);
  out_gemm_kernel<<<dim3(DM / 128, MROWS / 128), 256, 0, stream>>>(
      ows, Wo, (float*)d_out);
}